// Round 6
// baseline (5999.974 us; speedup 1.0000x reference)
//
#include <hip/hip_runtime.h>
#include <stdint.h>

typedef _Float16 h2 __attribute__((ext_vector_type(2)));
typedef float    f4 __attribute__((ext_vector_type(4)));
typedef uint32_t u4 __attribute__((ext_vector_type(4)));

#if __has_builtin(__builtin_amdgcn_fdot2)
__device__ __forceinline__ float dot2(uint32_t a, uint32_t b, float c) {
    return __builtin_amdgcn_fdot2(__builtin_bit_cast(h2, a),
                                  __builtin_bit_cast(h2, b), c, false);
}
#else
__device__ __forceinline__ float dot2(uint32_t a, uint32_t b, float c) {
    h2 ha = __builtin_bit_cast(h2, a), hb = __builtin_bit_cast(h2, b);
    return c + (float)ha[0]*(float)hb[0] + (float)ha[1]*(float)hb[1];
}
#endif

// tanh(z) = 1 - 2/(exp(2z)+1); v_exp_f32 + v_rcp path.
__device__ __forceinline__ float fast_tanh(float z) {
    float e = __expf(2.0f * z);
    return 1.0f - 2.0f * __builtin_amdgcn_rcpf(e + 1.0f);
}

#define TT 4096
#define NB 32
#define HD 512
#define JL 12              // k-pairs per col in LDS (98 KB total)
#define JTOT 64            // k-pairs per col total (128 k rows / 2)
#define JR (JTOT - JL)     // k-pairs per col in registers (52 -> 208 reg words)

// One step of the recurrence. Fully-unrolled j-loop with software-pipelined
// LDS reads: state quads (sq0/sq1, loaded 2 quads = ~8 iters ahead) and
// wstash quads (wq0..wq3, loaded 4 iters ahead). ds_read latency ~120 cyc;
// on-demand loads left only 16-64 cyc of covering work with 2 waves/SIMD ->
// ~900 cyc/step of VALU-idle stall in rounds 2/5. All register indices are
// static after unroll (rule: no runtime-indexed reg arrays).
#define STEP(TARG, OSAVE)                                                     \
  {                                                                           \
    const int t_ = (TARG);                                                    \
    const float nz = noise[(size_t)t_*(NB*HD) + nb];                          \
    const float x0 = Xb[t_*3 + 0];                                            \
    const float x1 = Xb[t_*3 + 1];                                            \
    const float x2 = Xb[t_*3 + 2];                                            \
    const u4* sv4 = (const u4*)((const uint32_t*)(&s_buf[cur][0]) + kg*64);   \
    float a0=0.f, a1=0.f, a2=0.f, a3=0.f;                                     \
    u4 sq0 = sv4[0], sq1 = sv4[1];                                            \
    u4 wq0 = wv[0*64], wq1 = wv[1*64], wq2 = wv[2*64], wq3 = wv[3*64];        \
    _Pragma("unroll")                                                         \
    for (int j = 0; j < JTOT; ++j) {                                          \
      const int q = j >> 2;                                                   \
      const u4 sqc = (q & 1) ? sq1 : sq0;                                     \
      const uint32_t sv = sqc[j & 3];                                         \
      if (j < JL) {                                                           \
        const u4 qq = ((j&3)==0) ? wq0 : ((j&3)==1) ? wq1 :                   \
                      ((j&3)==2) ? wq2 : wq3;                                 \
        a0 = dot2(sv, qq[0], a0);                                             \
        a1 = dot2(sv, qq[1], a1);                                             \
        a2 = dot2(sv, qq[2], a2);                                             \
        a3 = dot2(sv, qq[3], a3);                                             \
        if (j + 4 < JL) {                                                     \
          const u4 nq = wv[(j + 4) * 64];                                     \
          if ((j&3)==0) wq0 = nq; else if ((j&3)==1) wq1 = nq;                \
          else if ((j&3)==2) wq2 = nq; else wq3 = nq;                         \
        }                                                                     \
      } else {                                                                \
        const int jr = j - JL;                                                \
        a0 = dot2(sv, wreg[0][jr], a0);                                       \
        a1 = dot2(sv, wreg[1][jr], a1);                                       \
        a2 = dot2(sv, wreg[2][jr], a2);                                       \
        a3 = dot2(sv, wreg[3][jr], a3);                                       \
      }                                                                       \
      if ((j & 3) == 3 && q + 2 < 16) {                                       \
        const u4 ns = sv4[q + 2];                                             \
        if (q & 1) sq1 = ns; else sq0 = ns;                                   \
      }                                                                       \
    }                                                                         \
    f4 pv; pv[0]=a0; pv[1]=a1; pv[2]=a2; pv[3]=a3;                            \
    *(f4*)&pads[kg][c0] = pv;                                                 \
    __syncthreads();                                                          \
    float z = pads[0][tid] + pads[1][tid] + pads[2][tid] + pads[3][tid];      \
    z += win0*x0 + win1*x1 + win2*x2 + 0.01f*nz;                              \
    const float s_ = fast_tanh(z);                                            \
    (OSAVE) = s_;                                                             \
    s_buf[cur ^ 1][tid] = (_Float16)s_;                                       \
    __syncthreads();                                                          \
    cur ^= 1;                                                                 \
  }

// One block per batch row. 512 threads: kg = tid>>7 (k-slice of 128 state
// rows), colg = tid&127 (4 output columns). W_int resident as fp16 half2
// k-pairs: 12 pairs/col in LDS (ds_read_b128, conflict-free), 52 pairs/col
// in registers. State distribution: LDS-broadcast b128 quads. Out stores are
// batched 4 steps in registers and issued after barrier-2, so their vmcnt
// drain happens under the NEXT step's ~2000-cyc dot phase instead of
// serializing at the adjacent __syncthreads.
__global__ __launch_bounds__(512, 1)
void esn_kernel(const float* __restrict__ X, const float* __restrict__ W_in,
                const float* __restrict__ W_int, const float* __restrict__ noise,
                float* __restrict__ out)
{
    __shared__ __align__(16) _Float16 s_buf[2][HD];  // 2 KB (state fp16, dbuf)
    __shared__ float pads[4][HD];                    // 8 KB (per-kg partials)
    __shared__ u4 wstash[8 * JL * 64];               // 98 KB [wave][j][lane]

    const int tid  = threadIdx.x;
    const int b    = blockIdx.x;
    const int w    = tid >> 6;      // wave 0..7
    const int l    = tid & 63;      // lane 0..63
    const int kg   = tid >> 7;      // 0..3  (k-slice of 128 state rows)
    const int colg = tid & 127;     // 0..127
    const int c0   = colg * 4;      // first of this thread's 4 columns

    // Input weights for the reduce phase (col = tid).
    const float win0 = W_in[tid*3 + 0];
    const float win1 = W_in[tid*3 + 1];
    const float win2 = W_in[tid*3 + 2];

    // ---- Prologue: load + pack W_int (fp32 -> half2 k-pairs) ----
    uint32_t wreg[4][JR];
    {
        const f4* Wv = (const f4*)W_int;   // W_int[k][h], 4 cols at a time
        for (int j = 0; j < JL; ++j) {     // LDS part: k-pairs 0..JL-1
            const int k = kg*128 + 2*j;
            f4 r0 = Wv[(size_t)k*128 + colg];
            f4 r1 = Wv[(size_t)(k+1)*128 + colg];
            u4 q;
            #pragma unroll
            for (int c = 0; c < 4; ++c) {
                h2 hw; hw[0] = (_Float16)r0[c]; hw[1] = (_Float16)r1[c];
                q[c] = __builtin_bit_cast(uint32_t, hw);
            }
            wstash[(w*JL + j)*64 + l] = q;
        }
        #pragma unroll                      // register part (fully unrolled)
        for (int j = 0; j < JR; ++j) {
            const int k = kg*128 + 2*(JL + j);
            f4 r0 = Wv[(size_t)k*128 + colg];
            f4 r1 = Wv[(size_t)(k+1)*128 + colg];
            #pragma unroll
            for (int c = 0; c < 4; ++c) {
                h2 hw; hw[0] = (_Float16)r0[c]; hw[1] = (_Float16)r1[c];
                wreg[c][j] = __builtin_bit_cast(uint32_t, hw);
            }
        }
    }
    s_buf[0][tid] = (_Float16)0.01f;   // prev0 = 0.01
    __syncthreads();

    const float* Xb   = X   + (size_t)b * TT * 3;
    float*       outb = out + (size_t)b * TT * HD;
    const size_t nb   = (size_t)b * HD + tid;
    const u4*    wv   = &wstash[(w*JL)*64 + l];   // quad j at wv[j*64]

    int cur = 0;
    for (int t0 = 0; t0 < TT; t0 += 4) {
        float o0, o1, o2, o3;
        STEP(t0 + 0, o0);
        STEP(t0 + 1, o1);
        STEP(t0 + 2, o2);
        STEP(t0 + 3, o3);
        // Batched out stores: issued here, drained at the first barrier of
        // the NEXT step -> ~2000 cyc of dot work covers the store ack.
        float* op = outb + (size_t)t0 * HD + tid;
        op[0]      = o0;
        op[HD]     = o1;
        op[2 * HD] = o2;
        op[3 * HD] = o3;
    }
}

extern "C" void kernel_launch(void* const* d_in, const int* in_sizes, int n_in,
                              void* d_out, int out_size, void* d_ws, size_t ws_size,
                              hipStream_t stream)
{
    const float* X     = (const float*)d_in[0];
    const float* W_in  = (const float*)d_in[1];
    const float* W_int = (const float*)d_in[2];
    const float* noise = (const float*)d_in[3];
    float* out = (float*)d_out;

    esn_kernel<<<dim3(NB), dim3(512), 0, stream>>>(X, W_in, W_int, noise, out);
}